// Round 5
// baseline (305.828 us; speedup 1.0000x reference)
//
#include <hip/hip_runtime.h>
#include <hip/hip_bf16.h>

// MultiHeadSelfAttention on MI355X (gfx950)
// Pipeline: [f32->bf16 x] [fused transpose W -> bf16 N-major] -> 1x fused QKV
// MFMA GEMM (2-phase 128x128 dbuf glds kernel) -> MFMA flash attention vA
// (32x32x16, split-K qt>=8, glds K/V staging w/ pre-swizzled global source,
// permlane32_swap P-exchange, XCD swizzle) -> combine -> MFMA GEMM out-proj.
// R4: BK 64->32 in gemm_glds: LDS 64->32 KB => 5 blocks/CU (launch_bounds
//     (256,5)); doubles K-steps but the 2-phase barrier drain now overlaps
//     across 5 resident blocks (m114 inter-block TLP mechanism — the thing
//     R1's 1-block/CU pipeline destroyed). BK=32 XOR layout: LDS slot s of
//     row r holds k-chunk s^((r>>1)&3); read slot quad^((l16>>1)&3); glds
//     source pre-swizzled chunk (t&3)^((t>>3)&3) (row t>>2 and +64 share
//     the same swizzle — verified). Same 8-lane/16B-slot density as the
//     measured-zero-conflict BK=64 layout.

#define D_MODEL 1024
#define NHEADS  16
#define DK      64
#define BATCH   4
#define SEQ     2048
#define MROWS   (BATCH*SEQ)   // 8192

typedef short bvec8 __attribute__((ext_vector_type(8)));    // 8 bf16 = 4 VGPRs
typedef float fvec4  __attribute__((ext_vector_type(4)));   // 16x16 C/D frag
typedef float fvec16 __attribute__((ext_vector_type(16)));  // 32x32 C/D frag

__device__ __forceinline__ unsigned short f2bf(float f) {
    unsigned int x = __float_as_uint(f);
    x += 0x7fffu + ((x >> 16) & 1u);   // RNE
    return (unsigned short)(x >> 16);
}
__device__ __forceinline__ float bf2f(unsigned short u) {
    return __uint_as_float(((unsigned int)u) << 16);
}

__device__ __forceinline__ unsigned pack_bf16x2(float a, float b) {
#if __has_builtin(__builtin_amdgcn_cvt_pk_bf16_f32)
    typedef __bf16 bf16x2_t __attribute__((ext_vector_type(2)));
    union { bf16x2_t v; unsigned u; } cv;
    cv.v = __builtin_amdgcn_cvt_pk_bf16_f32(a, b);
    return cv.u;
#else
    return (unsigned)f2bf(a) | ((unsigned)f2bf(b) << 16);
#endif
}

__device__ __forceinline__ float fast_exp2(float x) {
#if __has_builtin(__builtin_amdgcn_exp2f)
    return __builtin_amdgcn_exp2f(x);      // single v_exp_f32
#else
    return exp2f(x);
#endif
}

// ---------------- prep kernels ----------------

__global__ void f32_to_bf16_k(const float* __restrict__ in,
                              unsigned short* __restrict__ out, int n4) {
    int i = blockIdx.x * 256 + threadIdx.x;
    if (i < n4) {
        float4 v = ((const float4*)in)[i];
        ushort4 o;
        o.x = f2bf(v.x); o.y = f2bf(v.y); o.z = f2bf(v.z); o.w = f2bf(v.w);
        ((ushort4*)out)[i] = o;
    }
}

// All 4 weight transposes in one launch: z picks the matrix.
__global__ void transpose_all_k(const float* __restrict__ wq, const float* __restrict__ wk,
                                const float* __restrict__ wv, const float* __restrict__ wo,
                                unsigned short* __restrict__ wqkvt,
                                unsigned short* __restrict__ wot) {
    __shared__ float tile[32][33];
    const int z = blockIdx.z;
    const float* W = (z == 0) ? wq : (z == 1) ? wk : (z == 2) ? wv : wo;
    unsigned short* Wt = (z == 3) ? wot : wqkvt + (size_t)z * D_MODEL * D_MODEL;
    int n0 = blockIdx.x * 32, k0 = blockIdx.y * 32;
    int tx = threadIdx.x & 31;
    int ty = (threadIdx.x >> 5) * 4;
#pragma unroll
    for (int i = 0; i < 4; ++i)
        tile[ty + i][tx] = W[(k0 + ty + i) * D_MODEL + n0 + tx];
    __syncthreads();
#pragma unroll
    for (int i = 0; i < 4; ++i)
        Wt[(n0 + ty + i) * D_MODEL + k0 + tx] = f2bf(tile[tx][ty + i]);
}

__global__ void build_cbias_k(const float* __restrict__ bq, const float* __restrict__ bk,
                              const float* __restrict__ bv, float* __restrict__ cb) {
    int i = blockIdx.x * 256 + threadIdx.x;   // 3072
    float v = (i < 1024) ? bq[i] : (i < 2048) ? bk[i - 1024] : bv[i - 2048];
    cb[i] = v;
}

// ---------------- bf16 MFMA GEMM, dbuf global_load_lds, BK=32 -------------
// T1 XCD swizzle (grids 1536 and 512, both %8==0). 5 blocks/CU.
__global__ __launch_bounds__(256, 5)
void gemm_glds(const unsigned short* __restrict__ A,
               const unsigned short* __restrict__ Bt,
               const float* __restrict__ bias,
               unsigned short* __restrict__ oq,
               unsigned short* __restrict__ ok,
               unsigned short* __restrict__ ov,
               float* __restrict__ of,
               float qscale, int mode) {
    __shared__ __align__(16) unsigned short As[2][128 * 32];  // 16 KB
    __shared__ __align__(16) unsigned short Bs[2][128 * 32];  // 16 KB

    const int tid  = threadIdx.x;
    const int lane = tid & 63;
    const int w    = tid >> 6;
    const int wr   = w >> 1, wc = w & 1;     // 2x2 waves, 64x64 each
    const int quad = lane >> 4, l16 = lane & 15;

    // XCD swizzle: hardware id h -> logical chunk (h&7)*cpx + h>>3
    const unsigned nwg = gridDim.x * gridDim.y;
    unsigned f = blockIdx.y * gridDim.x + blockIdx.x;
    f = (f & 7) * (nwg >> 3) + (f >> 3);
    const int rowBlock = (f / gridDim.x) * 128;
    const int colBlock = (f % gridDim.x) * 128;

    // staging: thread t owns LDS 16B-chunks t and t+256 of each 128x32 tile.
    // chunk c=(row<<2)|slot; slot s of row r holds logical k-chunk
    // s^((r>>1)&3)  => fetch global chunk (t&3)^((t>>3)&3); rows t>>2, +64.
    const int srow = tid >> 2;                       // 0..63
    const int gc   = (tid & 3) ^ ((tid >> 3) & 3);   // pre-swizzled k-chunk

#define G_STAGE(KOFF, BUF) do {                                               \
    const unsigned short* a0_ =                                               \
        &A[(size_t)(rowBlock + srow) * D_MODEL + (KOFF) + gc * 8];            \
    const unsigned short* b0_ =                                               \
        &Bt[(size_t)(colBlock + srow) * D_MODEL + (KOFF) + gc * 8];           \
    __builtin_amdgcn_global_load_lds(                                         \
        (const __attribute__((address_space(1))) void*)a0_,                   \
        (__attribute__((address_space(3))) void*)&As[BUF][tid * 8], 16, 0, 0); \
    __builtin_amdgcn_global_load_lds(                                         \
        (const __attribute__((address_space(1))) void*)(a0_ + (size_t)64 * D_MODEL), \
        (__attribute__((address_space(3))) void*)&As[BUF][(tid + 256) * 8], 16, 0, 0); \
    __builtin_amdgcn_global_load_lds(                                         \
        (const __attribute__((address_space(1))) void*)b0_,                   \
        (__attribute__((address_space(3))) void*)&Bs[BUF][tid * 8], 16, 0, 0); \
    __builtin_amdgcn_global_load_lds(                                         \
        (const __attribute__((address_space(1))) void*)(b0_ + (size_t)64 * D_MODEL), \
        (__attribute__((address_space(3))) void*)&Bs[BUF][(tid + 256) * 8], 16, 0, 0); \
} while (0)

    fvec4 acc[4][4] = {};
    const int sw = quad ^ ((l16 >> 1) & 3);   // read-side slot (lane-const)

    G_STAGE(0, 0);                            // prologue: tile 0 into buf 0

    for (int i = 0; i < 32; ++i) {            // K = 32 x 32
        __syncthreads();                      // tile i visible; buf^1 readers done
        const int buf = i & 1;
        if (i < 31) G_STAGE((i + 1) * 32, buf ^ 1);
        bvec8 af[4], bfr[4];
#pragma unroll
        for (int ii = 0; ii < 4; ++ii) {
            const int r = wr * 64 + ii * 16 + l16;
            af[ii] = *(const bvec8*)&As[buf][r * 32 + sw * 8];
        }
#pragma unroll
        for (int j = 0; j < 4; ++j) {
            const int r = wc * 64 + j * 16 + l16;
            bfr[j] = *(const bvec8*)&Bs[buf][r * 32 + sw * 8];
        }
#pragma unroll
        for (int ii = 0; ii < 4; ++ii)
#pragma unroll
            for (int j = 0; j < 4; ++j)
                acc[ii][j] = __builtin_amdgcn_mfma_f32_16x16x32_bf16(
                    af[ii], bfr[j], acc[ii][j], 0, 0, 0);
    }
#undef G_STAGE

    if (mode == 0) {
#pragma unroll
        for (int i = 0; i < 4; ++i) {
#pragma unroll
            for (int j = 0; j < 4; ++j) {
                int ncol = colBlock + wc * 64 + j * 16 + l16;
                int which = ncol >> 10;        // 0=Q 1=K 2=V (wave-uniform)
                int nn = ncol & 1023;
                int h = nn >> 6, d = nn & 63;
                float bv = bias[ncol];
#pragma unroll
                for (int r = 0; r < 4; ++r) {
                    int mrow = rowBlock + wr * 64 + i * 16 + quad * 4 + r;
                    int b = mrow >> 11, s = mrow & (SEQ - 1);
                    float v = acc[i][j][r] + bv;
                    if (which == 0)
                        oq[(((b * NHEADS + h) * SEQ + s) * DK) + d] = f2bf(v * qscale);
                    else if (which == 1)
                        ok[(((b * NHEADS + h) * SEQ + s) * DK) + d] = f2bf(v);
                    else
                        ov[(((b * NHEADS + h) * DK + d) * SEQ) + s] = f2bf(v);
                }
            }
        }
    } else {
#pragma unroll
        for (int i = 0; i < 4; ++i) {
#pragma unroll
            for (int j = 0; j < 4; ++j) {
                int ncol = colBlock + wc * 64 + j * 16 + l16;
                float bv = bias[ncol];
#pragma unroll
                for (int r = 0; r < 4; ++r) {
                    int mrow = rowBlock + wr * 64 + i * 16 + quad * 4 + r;
                    of[(size_t)mrow * D_MODEL + ncol] = acc[i][j][r] + bv;
                }
            }
        }
    }
}

// ---------------- MFMA flash attention vA (32x32x16, balanced split-K) -----
// grid (24,16,4), XCD-swizzled flat id (1536 % 8 == 0). bx decodes
// (heavy-first) via tables; qt 8..15 split into two key chunks.
// K/V staged via global_load_lds with pre-swizzled global source.
__global__ __launch_bounds__(256, 4)
void attn_mfmaA(const unsigned short* __restrict__ Q,   // (B,H,S,Dk) bf16, scaled
                const unsigned short* __restrict__ K,   // (B,H,S,Dk) bf16
                const unsigned short* __restrict__ Vt,  // (B,H,Dk,S) bf16
                unsigned short* __restrict__ O,         // (B,S,H*Dk) bf16
                unsigned short* __restrict__ Opart,     // [16][64][128][64] bf16
                float* __restrict__ Lpart) {            // [16][64][128] fp32
    __shared__ __align__(16) unsigned short Ksm[2][64 * 64];  // [key][dk] swizzled
    __shared__ __align__(16) unsigned short Vsm[2][64 * 64];  // [d][key] swizzled
    __shared__ float Lsh[4][32];

    const int tid  = threadIdx.x;
    const int lane = tid & 63;
    const int wq   = tid >> 6;
    const int hf   = lane >> 5;            // half-wave
    const int l32  = lane & 31;

    // XCD swizzle: logical f -> (bx, hh, b); XCD gets contiguous head-groups
    unsigned f = (blockIdx.z * 16 + blockIdx.y) * 24 + blockIdx.x;
    f = (f & 7) * 192 + (f >> 3);          // 1536/8 = 192
    const int bx = f % 24;
    const int hh = (f / 24) & 15;
    const int b  = f / 384;
    const int hb = b * NHEADS + hh;

    // work decode (heavy-first order; mode 2 = full, 0/1 = half)
    static const int qt_tbl[24] = {15,15,7,14,14,6,13,13,12,12,5,11,
                                   11,10,10,4,9,9,8,8,3,2,1,0};
    static const int md_tbl[24] = {0,1,2,0,1,2,0,1,0,1,2,0,
                                   1,0,1,2,0,1,0,1,2,2,2,2};
    const int qt = qt_tbl[bx];
    const int md = md_tbl[bx];
    const bool part = (md < 2);
    const int kt0 = (md == 1) ? qt + 1 : 0;
    const int kt1 = (md == 0) ? qt + 1 : 2 * qt + 2;
    const int slot = part ? ((qt - 8) * 2 + md) : 0;

    const size_t bhq = ((size_t)hb) * SEQ * DK;
    const unsigned short* Qb = Q + bhq;
    const unsigned short* Kb = K + bhq;
    const unsigned short* Vb = Vt + bhq;   // (Dk, S)

    const int q0 = qt * 128 + wq * 32;     // wave's first q row (global)

    // Q B-frags (32x32x16): B[k=dk=(hf*8+j)+kc*16][n=q=l32], kept in regs
    bvec8 qf[4];
#pragma unroll
    for (int kc = 0; kc < 4; ++kc)
        qf[kc] = *(const bvec8*)&Qb[(q0 + l32) * DK + kc * 16 + hf * 8];

    // glds staging: thread t owns 16B chunks t and t+256 of each 64x64 tile.
    // chunk c = row*8 + slot; slot holds global chunk slot^(row&7).
    const int r1 = tid >> 3;               // 0..31 (second row = r1+32, same &7)
    const int lcs = (tid & 7) ^ (r1 & 7);  // pre-swizzled global chunk index

#define ATTN_STAGE(KT, NB) do {                                               \
    const unsigned short* kg_ = Kb + ((KT) * 64 + r1) * DK + lcs * 8;         \
    const unsigned short* vg_ = Vb + (size_t)r1 * SEQ + (KT) * 64 + lcs * 8;  \
    __builtin_amdgcn_global_load_lds(                                         \
        (const __attribute__((address_space(1))) void*)kg_,                   \
        (__attribute__((address_space(3))) void*)&Ksm[NB][wq * 512], 16, 0, 0); \
    __builtin_amdgcn_global_load_lds(                                         \
        (const __attribute__((address_space(1))) void*)(kg_ + 32 * DK),       \
        (__attribute__((address_space(3))) void*)&Ksm[NB][2048 + wq * 512], 16, 0, 0); \
    __builtin_amdgcn_global_load_lds(                                         \
        (const __attribute__((address_space(1))) void*)vg_,                   \
        (__attribute__((address_space(3))) void*)&Vsm[NB][wq * 512], 16, 0, 0); \
    __builtin_amdgcn_global_load_lds(                                         \
        (const __attribute__((address_space(1))) void*)(vg_ + 32 * SEQ),      \
        (__attribute__((address_space(3))) void*)&Vsm[NB][2048 + wq * 512], 16, 0, 0); \
} while (0)

    const int ktact = 2 * qt + (wq >> 1);  // this wave's diagonal tile
    const int mofs  = (wq & 1) << 5;       // key offset for diagonal masking

    ATTN_STAGE(kt0, 0);                    // preload tile kt0 into buf 0

    fvec16 acc0 = {};                      // O[q=(r&3)+8*(r>>2)+4*hf][d=l32]
    fvec16 acc1 = {};                      // same, d=32+l32
    float lp = 0.f;                        // partial l for q=l32

    for (int kt = kt0; kt < kt1; ++kt) {
        __syncthreads();                   // drains vmcnt: tile kt visible;
                                           // buf^1 readers done (prev iter)
        const int buf = (kt - kt0) & 1;
        if (kt + 1 < kt1)                  // next tile in flight during compute
            ATTN_STAGE(kt + 1, buf ^ 1);
        if (kt <= ktact) {                 // wave-uniform: skip fully-masked tiles
            const unsigned short* Kbuf = &Ksm[buf][0];
            const unsigned short* Vbuf = &Vsm[buf][0];

            fvec16 s0 = {}, s1 = {};
            __builtin_amdgcn_s_setprio(1);     // T5: favor MFMA-issuing wave
#pragma unroll
            for (int kc = 0; kc < 4; ++kc) {
                const int ch = (((kc * 2 + hf) ^ (l32 & 7)) * 8);
                bvec8 a0 = *(const bvec8*)&Kbuf[l32 * 64 + ch];
                bvec8 a1 = *(const bvec8*)&Kbuf[(32 + l32) * 64 + ch];
                s0 = __builtin_amdgcn_mfma_f32_32x32x16_bf16(a0, qf[kc], s0, 0, 0, 0);
                s1 = __builtin_amdgcn_mfma_f32_32x32x16_bf16(a1, qf[kc], s1, 0, 0, 0);
            }
            __builtin_amdgcn_s_setprio(0);

            if (kt == ktact) {             // diagonal tile: mask key > q
#pragma unroll
                for (int r = 0; r < 16; ++r) {
                    const int key0 = (r & 3) + 8 * (r >> 2) + 4 * hf - mofs;
                    if (key0 > l32)      s0[r] = -__builtin_inff();
                    if (key0 + 32 > l32) s1[r] = -__builtin_inff();
                }
            }

            unsigned pk[16];
#pragma unroll
            for (int m = 0; m < 8; ++m) {
                float p0 = fast_exp2(s0[2 * m]);
                float p1 = fast_exp2(s0[2 * m + 1]);
                float p2 = fast_exp2(s1[2 * m]);
                float p3 = fast_exp2(s1[2 * m + 1]);
                lp += (p0 + p1) + (p2 + p3);
                pk[m]     = pack_bf16x2(p0, p1);
                pk[8 + m] = pack_bf16x2(p2, p3);
            }

            __builtin_amdgcn_s_setprio(1);     // T5: PV MFMA cluster
#pragma unroll
            for (int kc16 = 0; kc16 < 4; ++kc16) {
                const int b0 = (kc16 >> 1) * 8 + (kc16 & 1) * 4;
                union { unsigned u[4]; bvec8 v; } afu;
#if __has_builtin(__builtin_amdgcn_permlane32_swap)
                // a'={a_lo,b_lo}, b'={a_hi,b_hi}:
                //   (pk0,pk2) -> afu.u[0], afu.u[2]; (pk1,pk3) -> u[1], u[3]
                {
                    auto r02 = __builtin_amdgcn_permlane32_swap(
                        pk[b0 + 0], pk[b0 + 2], false, false);
                    auto r13 = __builtin_amdgcn_permlane32_swap(
                        pk[b0 + 1], pk[b0 + 3], false, false);
                    unsigned o02[2], o13[2];
                    __builtin_memcpy(o02, &r02, 8);
                    __builtin_memcpy(o13, &r13, 8);
                    afu.u[0] = o02[0]; afu.u[2] = o02[1];
                    afu.u[1] = o13[0]; afu.u[3] = o13[1];
                }
#else
                {
                    unsigned sw0 = __shfl_xor(pk[b0 + 0], 32);
                    unsigned sw1 = __shfl_xor(pk[b0 + 1], 32);
                    unsigned sw2 = __shfl_xor(pk[b0 + 2], 32);
                    unsigned sw3 = __shfl_xor(pk[b0 + 3], 32);
                    afu.u[0] = hf ? sw2 : pk[b0 + 0];
                    afu.u[1] = hf ? sw3 : pk[b0 + 1];
                    afu.u[2] = hf ? pk[b0 + 2] : sw0;
                    afu.u[3] = hf ? pk[b0 + 3] : sw1;
                }
#endif
                const int ch = (((kc16 * 2 + hf) ^ (l32 & 7)) * 8);
                bvec8 bv0 = *(const bvec8*)&Vbuf[l32 * 64 + ch];
                bvec8 bv1 = *(const bvec8*)&Vbuf[(32 + l32) * 64 + ch];
                acc0 = __builtin_amdgcn_mfma_f32_32x32x16_bf16(afu.v, bv0, acc0, 0, 0, 0);
                acc1 = __builtin_amdgcn_mfma_f32_32x32x16_bf16(afu.v, bv1, acc1, 0, 0, 0);
            }
            __builtin_amdgcn_s_setprio(0);
        }
    }
#undef ATTN_STAGE

    const float l = lp + __shfl_xor(lp, 32);   // l(q=l32), replicated per half

    if (part) {
        // unnormalized partials: bf16 O (additive across chunks) + fp32 l
        if (lane < 32)
            Lpart[((size_t)slot * 64 + hb) * 128 + wq * 32 + l32] = l;
        unsigned short* Od = Opart + (((size_t)slot * 64 + hb) * 128 + wq * 32) * 64;
#pragma unroll
        for (int g = 0; g < 4; ++g)
#pragma unroll
            for (int rr = 0; rr < 4; ++rr) {
                const int reg = g * 4 + rr;
                const int qrl = g * 8 + 4 * hf + rr;
                Od[(size_t)qrl * 64 + l32]      = f2bf(acc0[reg]);
                Od[(size_t)qrl * 64 + 32 + l32] = f2bf(acc1[reg]);
            }
    } else {
        if (lane < 32) Lsh[wq][l32] = l;   // same-wave LDS dep (lgkmcnt)
#pragma unroll
        for (int g = 0; g < 4; ++g) {
            float4 lv = *(const float4*)&Lsh[wq][g * 8 + 4 * hf];
#pragma unroll
            for (int rr = 0; rr < 4; ++rr) {
                const int reg = g * 4 + rr;
                const int qrow = q0 + g * 8 + 4 * hf + rr;
                const float inv = 1.f / ((const float*)&lv)[rr];
                unsigned short* dst = O + (size_t)(b * SEQ + qrow) * D_MODEL + hh * DK + l32;
                dst[0]  = f2bf(acc0[reg] * inv);
                dst[32] = f2bf(acc1[reg] * inv);
            }
        }
    }
}

// combine the two key-chunks for qt in [8,16): O = (Oa+Ob)/(la+lb) -> bf16
__global__ void attn_combine_k(const unsigned short* __restrict__ Opart,
                               const float* __restrict__ Lpart,
                               unsigned short* __restrict__ O) {
    const int qt = 8 + blockIdx.x;
    const int h = blockIdx.y, b = blockIdx.z;
    const int hb = b * NHEADS + h;
    const int s0 = (qt - 8) * 2;
    const unsigned short* A  = Opart + ((size_t)(s0)*64 + hb) * 128 * 64;
    const unsigned short* Bp = Opart + ((size_t)(s0 + 1) * 64 + hb) * 128 * 64;
    const float* LA = Lpart + ((size_t)(s0)*64 + hb) * 128;
    const float* LB = Lpart + ((size_t)(s0 + 1) * 64 + hb) * 128;
    for (int e = threadIdx.x; e < 128 * 64; e += 256) {
        const int qr = e >> 6, d = e & 63;
        const float inv = 1.f / (LA[qr] + LB[qr]);
        const float v = (bf2f(A[e]) + bf2f(Bp[e])) * inv;
        O[(size_t)(b * SEQ + qt * 128 + qr) * D_MODEL + h * DK + d] = f2bf(v);
    }
}

// ---------------- launch ----------------

extern "C" void kernel_launch(void* const* d_in, const int* in_sizes, int n_in,
                              void* d_out, int out_size, void* d_ws, size_t ws_size,
                              hipStream_t stream) {
    const float* x  = (const float*)d_in[0];
    const float* wq = (const float*)d_in[1];
    const float* bq = (const float*)d_in[2];
    const float* wk = (const float*)d_in[3];
    const float* bk = (const float*)d_in[4];
    const float* wv = (const float*)d_in[5];
    const float* bv = (const float*)d_in[6];
    const float* wo = (const float*)d_in[7];
    const float* bo = (const float*)d_in[8];
    float* out = (float*)d_out;

    char* ws = (char*)d_ws;
    const size_t MB = 1u << 20;
    unsigned short* xb    = (unsigned short*)(ws);            // 16 MB  x bf16
    unsigned short* wqkvt = (unsigned short*)(ws + 16 * MB);  //  6 MB  [Wq;Wk;Wv]^T
    unsigned short* wot   = (unsigned short*)(ws + 22 * MB);  //  2 MB (live thru out-proj)
    unsigned short* qb    = (unsigned short*)(ws + 24 * MB);  // 16 MB each
    unsigned short* kb    = (unsigned short*)(ws + 40 * MB);
    unsigned short* vtb   = (unsigned short*)(ws + 56 * MB);  // V^T (B,H,Dk,S)
    unsigned short* ab    = (unsigned short*)(ws + 72 * MB);  // attn out, ends 88 MB
    float* cbias = (float*)(ws + 72 * MB);  // 12 KB, consumed by QKV GEMM
    // split-K partials overlay xb/wqkvt (dead after the QKV GEMM):
    unsigned short* Opart = (unsigned short*)(ws);  // 16 MB [16][64][128][64] bf16
    float* Lpart = (float*)(ws + 16 * MB);          // 512 KB [16][64][128] fp32

    f32_to_bf16_k<<<(MROWS * D_MODEL / 4 + 255) / 256, 256, 0, stream>>>(
        x, xb, MROWS * D_MODEL / 4);
    transpose_all_k<<<dim3(32, 32, 4), 256, 0, stream>>>(wq, wk, wv, wo, wqkvt, wot);
    build_cbias_k<<<12, 256, 0, stream>>>(bq, bk, bv, cbias);

    // Q pre-scale folds softmax's 1/sqrt(Dk) AND log2(e) for exp2-domain softmax
    const float QSCALE = 0.125f * 1.44269504088896340736f;

    // fused QKV projection: N = 3072
    gemm_glds<<<dim3(3072 / 128, MROWS / 128), 256, 0, stream>>>(
        xb, wqkvt, cbias, qb, kb, vtb, nullptr, QSCALE, 0);

    attn_mfmaA<<<dim3(24, NHEADS, BATCH), 256, 0, stream>>>(
        qb, kb, vtb, ab, Opart, Lpart);
    attn_combine_k<<<dim3(8, NHEADS, BATCH), 256, 0, stream>>>(Opart, Lpart, ab);

    // out projection: fp32 output + bias
    gemm_glds<<<dim3(D_MODEL / 128, MROWS / 128), 256, 0, stream>>>(
        ab, wot, bo, nullptr, nullptr, nullptr, out, 1.0f, 1);
}

// Round 6
// 262.576 us; speedup vs baseline: 1.1647x; 1.1647x over previous
//
#include <hip/hip_runtime.h>
#include <hip/hip_bf16.h>

// MultiHeadSelfAttention on MI355X (gfx950)
// Pipeline: [f32->bf16 x] [fused transpose W -> bf16 N-major] -> 1x fused QKV
// MFMA GEMM (2-phase 128x128 BK=64 dbuf glds kernel — R4's BK=32/5-block
// variant refuted: VGPR clamp 88->48 + halved MFMA-per-barrier outweighed
// occupancy 17->31%) -> MFMA flash attention vA (32x32x16, split-K qt>=8,
// glds K/V staging w/ pre-swizzled global source, permlane32_swap
// P-exchange, XCD swizzle) -> combine -> MFMA GEMM out-proj.
// R5: revert GEMM to R3-exact; vectorize combine (ushort4, G13); pack the
//     V^T epilogue store (4 consecutive s per thread -> 1 ushort4 store).

#define D_MODEL 1024
#define NHEADS  16
#define DK      64
#define BATCH   4
#define SEQ     2048
#define MROWS   (BATCH*SEQ)   // 8192

typedef short bvec8 __attribute__((ext_vector_type(8)));    // 8 bf16 = 4 VGPRs
typedef float fvec4  __attribute__((ext_vector_type(4)));   // 16x16 C/D frag
typedef float fvec16 __attribute__((ext_vector_type(16)));  // 32x32 C/D frag

__device__ __forceinline__ unsigned short f2bf(float f) {
    unsigned int x = __float_as_uint(f);
    x += 0x7fffu + ((x >> 16) & 1u);   // RNE
    return (unsigned short)(x >> 16);
}
__device__ __forceinline__ float bf2f(unsigned short u) {
    return __uint_as_float(((unsigned int)u) << 16);
}

__device__ __forceinline__ unsigned pack_bf16x2(float a, float b) {
#if __has_builtin(__builtin_amdgcn_cvt_pk_bf16_f32)
    typedef __bf16 bf16x2_t __attribute__((ext_vector_type(2)));
    union { bf16x2_t v; unsigned u; } cv;
    cv.v = __builtin_amdgcn_cvt_pk_bf16_f32(a, b);
    return cv.u;
#else
    return (unsigned)f2bf(a) | ((unsigned)f2bf(b) << 16);
#endif
}

__device__ __forceinline__ float fast_exp2(float x) {
#if __has_builtin(__builtin_amdgcn_exp2f)
    return __builtin_amdgcn_exp2f(x);      // single v_exp_f32
#else
    return exp2f(x);
#endif
}

// ---------------- prep kernels ----------------

__global__ void f32_to_bf16_k(const float* __restrict__ in,
                              unsigned short* __restrict__ out, int n4) {
    int i = blockIdx.x * 256 + threadIdx.x;
    if (i < n4) {
        float4 v = ((const float4*)in)[i];
        ushort4 o;
        o.x = f2bf(v.x); o.y = f2bf(v.y); o.z = f2bf(v.z); o.w = f2bf(v.w);
        ((ushort4*)out)[i] = o;
    }
}

// All 4 weight transposes in one launch: z picks the matrix.
__global__ void transpose_all_k(const float* __restrict__ wq, const float* __restrict__ wk,
                                const float* __restrict__ wv, const float* __restrict__ wo,
                                unsigned short* __restrict__ wqkvt,
                                unsigned short* __restrict__ wot) {
    __shared__ float tile[32][33];
    const int z = blockIdx.z;
    const float* W = (z == 0) ? wq : (z == 1) ? wk : (z == 2) ? wv : wo;
    unsigned short* Wt = (z == 3) ? wot : wqkvt + (size_t)z * D_MODEL * D_MODEL;
    int n0 = blockIdx.x * 32, k0 = blockIdx.y * 32;
    int tx = threadIdx.x & 31;
    int ty = (threadIdx.x >> 5) * 4;
#pragma unroll
    for (int i = 0; i < 4; ++i)
        tile[ty + i][tx] = W[(k0 + ty + i) * D_MODEL + n0 + tx];
    __syncthreads();
#pragma unroll
    for (int i = 0; i < 4; ++i)
        Wt[(n0 + ty + i) * D_MODEL + k0 + tx] = f2bf(tile[tx][ty + i]);
}

__global__ void build_cbias_k(const float* __restrict__ bq, const float* __restrict__ bk,
                              const float* __restrict__ bv, float* __restrict__ cb) {
    int i = blockIdx.x * 256 + threadIdx.x;   // 3072
    float v = (i < 1024) ? bq[i] : (i < 2048) ? bk[i - 1024] : bv[i - 2048];
    cb[i] = v;
}

// ---------------- bf16 MFMA GEMM, dbuf global_load_lds (R3-exact) ---------
// T1: XCD-aware swizzle of the flat block id (grids 1536 and 512, both %8==0).
__global__ __launch_bounds__(256, 2)
void gemm_glds(const unsigned short* __restrict__ A,
               const unsigned short* __restrict__ Bt,
               const float* __restrict__ bias,
               unsigned short* __restrict__ oq,
               unsigned short* __restrict__ ok,
               unsigned short* __restrict__ ov,
               float* __restrict__ of,
               float qscale, int mode) {
    __shared__ __align__(16) unsigned short As[2][128 * 64];
    __shared__ __align__(16) unsigned short Bs[2][128 * 64];

    const int tid  = threadIdx.x;
    const int lane = tid & 63;
    const int w    = tid >> 6;
    const int wr   = w >> 1, wc = w & 1;     // 2x2 waves, 64x64 each
    const int quad = lane >> 4, l16 = lane & 15;

    // XCD swizzle: hardware id h -> logical chunk (h&7)*cpx + h>>3
    const unsigned nwg = gridDim.x * gridDim.y;
    unsigned f = blockIdx.y * gridDim.x + blockIdx.x;
    f = (f & 7) * (nwg >> 3) + (f >> 3);
    const int rowBlock = (f / gridDim.x) * 128;
    const int colBlock = (f % gridDim.x) * 128;

    const int lrow   = lane >> 3;
    const int gchunk = (lane & 7) ^ lrow;

    fvec4 acc[4][4] = {};

    {   // prologue: issue tile 0 into buf 0
#pragma unroll
        for (int n = 0; n < 4; ++n) {
            const int g = w * 4 + n;
            __builtin_amdgcn_global_load_lds(
                (const __attribute__((address_space(1))) void*)
                    &A[(size_t)(rowBlock + g * 8 + lrow) * D_MODEL + gchunk * 8],
                (__attribute__((address_space(3))) void*)&As[0][g * 512], 16, 0, 0);
            __builtin_amdgcn_global_load_lds(
                (const __attribute__((address_space(1))) void*)
                    &Bt[(size_t)(colBlock + g * 8 + lrow) * D_MODEL + gchunk * 8],
                (__attribute__((address_space(3))) void*)&Bs[0][g * 512], 16, 0, 0);
        }
    }

    for (int i = 0; i < 16; ++i) {             // K = 16 x 64
        __syncthreads();                       // tile i visible; buf^1 readers done
        const int buf = i & 1;
        if (i < 15) {                          // tile i+1 in flight during compute
            const int k1 = (i + 1) * 64;
#pragma unroll
            for (int n = 0; n < 4; ++n) {
                const int g = w * 4 + n;
                __builtin_amdgcn_global_load_lds(
                    (const __attribute__((address_space(1))) void*)
                        &A[(size_t)(rowBlock + g * 8 + lrow) * D_MODEL + k1 + gchunk * 8],
                    (__attribute__((address_space(3))) void*)&As[buf ^ 1][g * 512], 16, 0, 0);
                __builtin_amdgcn_global_load_lds(
                    (const __attribute__((address_space(1))) void*)
                        &Bt[(size_t)(colBlock + g * 8 + lrow) * D_MODEL + k1 + gchunk * 8],
                    (__attribute__((address_space(3))) void*)&Bs[buf ^ 1][g * 512], 16, 0, 0);
            }
        }
#pragma unroll
        for (int kc = 0; kc < 2; ++kc) {
            bvec8 af[4], bfr[4];
#pragma unroll
            for (int ii = 0; ii < 4; ++ii) {
                int r = wr * 64 + ii * 16 + l16;
                af[ii] = *(const bvec8*)&As[buf][r * 64 + (((kc * 4 + quad) ^ (l16 & 7)) * 8)];
            }
#pragma unroll
            for (int j = 0; j < 4; ++j) {
                int r = wc * 64 + j * 16 + l16;
                bfr[j] = *(const bvec8*)&Bs[buf][r * 64 + (((kc * 4 + quad) ^ (l16 & 7)) * 8)];
            }
#pragma unroll
            for (int ii = 0; ii < 4; ++ii)
#pragma unroll
                for (int j = 0; j < 4; ++j)
                    acc[ii][j] = __builtin_amdgcn_mfma_f32_16x16x32_bf16(
                        af[ii], bfr[j], acc[ii][j], 0, 0, 0);
        }
    }

    if (mode == 0) {
#pragma unroll
        for (int i = 0; i < 4; ++i) {
#pragma unroll
            for (int j = 0; j < 4; ++j) {
                int ncol = colBlock + wc * 64 + j * 16 + l16;
                int which = ncol >> 10;        // 0=Q 1=K 2=V (wave-uniform)
                int nn = ncol & 1023;
                int h = nn >> 6, d = nn & 63;
                float bv = bias[ncol];
                if (which == 2) {
                    // V^T: 4 consecutive s per thread -> one ushort4 store
                    const int mrow0 = rowBlock + wr * 64 + i * 16 + quad * 4;
                    const int b = mrow0 >> 11, s0 = mrow0 & (SEQ - 1);
                    ushort4 pv;
                    pv.x = f2bf(acc[i][j][0] + bv);
                    pv.y = f2bf(acc[i][j][1] + bv);
                    pv.z = f2bf(acc[i][j][2] + bv);
                    pv.w = f2bf(acc[i][j][3] + bv);
                    *(ushort4*)&ov[(((size_t)(b * NHEADS + h) * DK + d) * SEQ) + s0] = pv;
                } else {
#pragma unroll
                    for (int r = 0; r < 4; ++r) {
                        int mrow = rowBlock + wr * 64 + i * 16 + quad * 4 + r;
                        int b = mrow >> 11, s = mrow & (SEQ - 1);
                        float v = acc[i][j][r] + bv;
                        if (which == 0)
                            oq[(((b * NHEADS + h) * SEQ + s) * DK) + d] = f2bf(v * qscale);
                        else
                            ok[(((b * NHEADS + h) * SEQ + s) * DK) + d] = f2bf(v);
                    }
                }
            }
        }
    } else {
#pragma unroll
        for (int i = 0; i < 4; ++i) {
#pragma unroll
            for (int j = 0; j < 4; ++j) {
                int ncol = colBlock + wc * 64 + j * 16 + l16;
                float bv = bias[ncol];
#pragma unroll
                for (int r = 0; r < 4; ++r) {
                    int mrow = rowBlock + wr * 64 + i * 16 + quad * 4 + r;
                    of[(size_t)mrow * D_MODEL + ncol] = acc[i][j][r] + bv;
                }
            }
        }
    }
}

// ---------------- MFMA flash attention vA (32x32x16, balanced split-K) -----
// grid (24,16,4), XCD-swizzled flat id (1536 % 8 == 0). bx decodes
// (heavy-first) via tables; qt 8..15 split into two key chunks.
// K/V staged via global_load_lds with pre-swizzled global source.
__global__ __launch_bounds__(256, 4)
void attn_mfmaA(const unsigned short* __restrict__ Q,   // (B,H,S,Dk) bf16, scaled
                const unsigned short* __restrict__ K,   // (B,H,S,Dk) bf16
                const unsigned short* __restrict__ Vt,  // (B,H,Dk,S) bf16
                unsigned short* __restrict__ O,         // (B,S,H*Dk) bf16
                unsigned short* __restrict__ Opart,     // [16][64][128][64] bf16
                float* __restrict__ Lpart) {            // [16][64][128] fp32
    __shared__ __align__(16) unsigned short Ksm[2][64 * 64];  // [key][dk] swizzled
    __shared__ __align__(16) unsigned short Vsm[2][64 * 64];  // [d][key] swizzled
    __shared__ float Lsh[4][32];

    const int tid  = threadIdx.x;
    const int lane = tid & 63;
    const int wq   = tid >> 6;
    const int hf   = lane >> 5;            // half-wave
    const int l32  = lane & 31;

    // XCD swizzle: logical f -> (bx, hh, b); XCD gets contiguous head-groups
    unsigned f = (blockIdx.z * 16 + blockIdx.y) * 24 + blockIdx.x;
    f = (f & 7) * 192 + (f >> 3);          // 1536/8 = 192
    const int bx = f % 24;
    const int hh = (f / 24) & 15;
    const int b  = f / 384;
    const int hb = b * NHEADS + hh;

    // work decode (heavy-first order; mode 2 = full, 0/1 = half)
    static const int qt_tbl[24] = {15,15,7,14,14,6,13,13,12,12,5,11,
                                   11,10,10,4,9,9,8,8,3,2,1,0};
    static const int md_tbl[24] = {0,1,2,0,1,2,0,1,0,1,2,0,
                                   1,0,1,2,0,1,0,1,2,2,2,2};
    const int qt = qt_tbl[bx];
    const int md = md_tbl[bx];
    const bool part = (md < 2);
    const int kt0 = (md == 1) ? qt + 1 : 0;
    const int kt1 = (md == 0) ? qt + 1 : 2 * qt + 2;
    const int slot = part ? ((qt - 8) * 2 + md) : 0;

    const size_t bhq = ((size_t)hb) * SEQ * DK;
    const unsigned short* Qb = Q + bhq;
    const unsigned short* Kb = K + bhq;
    const unsigned short* Vb = Vt + bhq;   // (Dk, S)

    const int q0 = qt * 128 + wq * 32;     // wave's first q row (global)

    // Q B-frags (32x32x16): B[k=dk=(hf*8+j)+kc*16][n=q=l32], kept in regs
    bvec8 qf[4];
#pragma unroll
    for (int kc = 0; kc < 4; ++kc)
        qf[kc] = *(const bvec8*)&Qb[(q0 + l32) * DK + kc * 16 + hf * 8];

    // glds staging: thread t owns 16B chunks t and t+256 of each 64x64 tile.
    // chunk c = row*8 + slot; slot holds global chunk slot^(row&7).
    const int r1 = tid >> 3;               // 0..31 (second row = r1+32, same &7)
    const int lcs = (tid & 7) ^ (r1 & 7);  // pre-swizzled global chunk index

#define ATTN_STAGE(KT, NB) do {                                               \
    const unsigned short* kg_ = Kb + ((KT) * 64 + r1) * DK + lcs * 8;         \
    const unsigned short* vg_ = Vb + (size_t)r1 * SEQ + (KT) * 64 + lcs * 8;  \
    __builtin_amdgcn_global_load_lds(                                         \
        (const __attribute__((address_space(1))) void*)kg_,                   \
        (__attribute__((address_space(3))) void*)&Ksm[NB][wq * 512], 16, 0, 0); \
    __builtin_amdgcn_global_load_lds(                                         \
        (const __attribute__((address_space(1))) void*)(kg_ + 32 * DK),       \
        (__attribute__((address_space(3))) void*)&Ksm[NB][2048 + wq * 512], 16, 0, 0); \
    __builtin_amdgcn_global_load_lds(                                         \
        (const __attribute__((address_space(1))) void*)vg_,                   \
        (__attribute__((address_space(3))) void*)&Vsm[NB][wq * 512], 16, 0, 0); \
    __builtin_amdgcn_global_load_lds(                                         \
        (const __attribute__((address_space(1))) void*)(vg_ + 32 * SEQ),      \
        (__attribute__((address_space(3))) void*)&Vsm[NB][2048 + wq * 512], 16, 0, 0); \
} while (0)

    const int ktact = 2 * qt + (wq >> 1);  // this wave's diagonal tile
    const int mofs  = (wq & 1) << 5;       // key offset for diagonal masking

    ATTN_STAGE(kt0, 0);                    // preload tile kt0 into buf 0

    fvec16 acc0 = {};                      // O[q=(r&3)+8*(r>>2)+4*hf][d=l32]
    fvec16 acc1 = {};                      // same, d=32+l32
    float lp = 0.f;                        // partial l for q=l32

    for (int kt = kt0; kt < kt1; ++kt) {
        __syncthreads();                   // drains vmcnt: tile kt visible;
                                           // buf^1 readers done (prev iter)
        const int buf = (kt - kt0) & 1;
        if (kt + 1 < kt1)                  // next tile in flight during compute
            ATTN_STAGE(kt + 1, buf ^ 1);
        if (kt <= ktact) {                 // wave-uniform: skip fully-masked tiles
            const unsigned short* Kbuf = &Ksm[buf][0];
            const unsigned short* Vbuf = &Vsm[buf][0];

            fvec16 s0 = {}, s1 = {};
            __builtin_amdgcn_s_setprio(1);     // T5: favor MFMA-issuing wave
#pragma unroll
            for (int kc = 0; kc < 4; ++kc) {
                const int ch = (((kc * 2 + hf) ^ (l32 & 7)) * 8);
                bvec8 a0 = *(const bvec8*)&Kbuf[l32 * 64 + ch];
                bvec8 a1 = *(const bvec8*)&Kbuf[(32 + l32) * 64 + ch];
                s0 = __builtin_amdgcn_mfma_f32_32x32x16_bf16(a0, qf[kc], s0, 0, 0, 0);
                s1 = __builtin_amdgcn_mfma_f32_32x32x16_bf16(a1, qf[kc], s1, 0, 0, 0);
            }
            __builtin_amdgcn_s_setprio(0);

            if (kt == ktact) {             // diagonal tile: mask key > q
#pragma unroll
                for (int r = 0; r < 16; ++r) {
                    const int key0 = (r & 3) + 8 * (r >> 2) + 4 * hf - mofs;
                    if (key0 > l32)      s0[r] = -__builtin_inff();
                    if (key0 + 32 > l32) s1[r] = -__builtin_inff();
                }
            }

            unsigned pk[16];
#pragma unroll
            for (int m = 0; m < 8; ++m) {
                float p0 = fast_exp2(s0[2 * m]);
                float p1 = fast_exp2(s0[2 * m + 1]);
                float p2 = fast_exp2(s1[2 * m]);
                float p3 = fast_exp2(s1[2 * m + 1]);
                lp += (p0 + p1) + (p2 + p3);
                pk[m]     = pack_bf16x2(p0, p1);
                pk[8 + m] = pack_bf16x2(p2, p3);
            }

            __builtin_amdgcn_s_setprio(1);     // T5: PV MFMA cluster
#pragma unroll
            for (int kc16 = 0; kc16 < 4; ++kc16) {
                const int b0 = (kc16 >> 1) * 8 + (kc16 & 1) * 4;
                union { unsigned u[4]; bvec8 v; } afu;
#if __has_builtin(__builtin_amdgcn_permlane32_swap)
                // a'={a_lo,b_lo}, b'={a_hi,b_hi}:
                //   (pk0,pk2) -> afu.u[0], afu.u[2]; (pk1,pk3) -> u[1], u[3]
                {
                    auto r02 = __builtin_amdgcn_permlane32_swap(
                        pk[b0 + 0], pk[b0 + 2], false, false);
                    auto r13 = __builtin_amdgcn_permlane32_swap(
                        pk[b0 + 1], pk[b0 + 3], false, false);
                    unsigned o02[2], o13[2];
                    __builtin_memcpy(o02, &r02, 8);
                    __builtin_memcpy(o13, &r13, 8);
                    afu.u[0] = o02[0]; afu.u[2] = o02[1];
                    afu.u[1] = o13[0]; afu.u[3] = o13[1];
                }
#else
                {
                    unsigned sw0 = __shfl_xor(pk[b0 + 0], 32);
                    unsigned sw1 = __shfl_xor(pk[b0 + 1], 32);
                    unsigned sw2 = __shfl_xor(pk[b0 + 2], 32);
                    unsigned sw3 = __shfl_xor(pk[b0 + 3], 32);
                    afu.u[0] = hf ? sw2 : pk[b0 + 0];
                    afu.u[1] = hf ? sw3 : pk[b0 + 1];
                    afu.u[2] = hf ? pk[b0 + 2] : sw0;
                    afu.u[3] = hf ? pk[b0 + 3] : sw1;
                }
#endif
                const int ch = (((kc16 * 2 + hf) ^ (l32 & 7)) * 8);
                bvec8 bv0 = *(const bvec8*)&Vbuf[l32 * 64 + ch];
                bvec8 bv1 = *(const bvec8*)&Vbuf[(32 + l32) * 64 + ch];
                acc0 = __builtin_amdgcn_mfma_f32_32x32x16_bf16(afu.v, bv0, acc0, 0, 0, 0);
                acc1 = __builtin_amdgcn_mfma_f32_32x32x16_bf16(afu.v, bv1, acc1, 0, 0, 0);
            }
            __builtin_amdgcn_s_setprio(0);
        }
    }
#undef ATTN_STAGE

    const float l = lp + __shfl_xor(lp, 32);   // l(q=l32), replicated per half

    if (part) {
        // unnormalized partials: bf16 O (additive across chunks) + fp32 l
        if (lane < 32)
            Lpart[((size_t)slot * 64 + hb) * 128 + wq * 32 + l32] = l;
        unsigned short* Od = Opart + (((size_t)slot * 64 + hb) * 128 + wq * 32) * 64;
#pragma unroll
        for (int g = 0; g < 4; ++g)
#pragma unroll
            for (int rr = 0; rr < 4; ++rr) {
                const int reg = g * 4 + rr;
                const int qrl = g * 8 + 4 * hf + rr;
                Od[(size_t)qrl * 64 + l32]      = f2bf(acc0[reg]);
                Od[(size_t)qrl * 64 + 32 + l32] = f2bf(acc1[reg]);
            }
    } else {
        if (lane < 32) Lsh[wq][l32] = l;   // same-wave LDS dep (lgkmcnt)
#pragma unroll
        for (int g = 0; g < 4; ++g) {
            float4 lv = *(const float4*)&Lsh[wq][g * 8 + 4 * hf];
#pragma unroll
            for (int rr = 0; rr < 4; ++rr) {
                const int reg = g * 4 + rr;
                const int qrow = q0 + g * 8 + 4 * hf + rr;
                const float inv = 1.f / ((const float*)&lv)[rr];
                unsigned short* dst = O + (size_t)(b * SEQ + qrow) * D_MODEL + hh * DK + l32;
                dst[0]  = f2bf(acc0[reg] * inv);
                dst[32] = f2bf(acc1[reg] * inv);
            }
        }
    }
}

// combine the two key-chunks for qt in [8,16): O = (Oa+Ob)/(la+lb) -> bf16
// R5: vectorized ushort4 loads/stores (G13).
__global__ void attn_combine_k(const unsigned short* __restrict__ Opart,
                               const float* __restrict__ Lpart,
                               unsigned short* __restrict__ O) {
    const int qt = 8 + blockIdx.x;
    const int h = blockIdx.y, b = blockIdx.z;
    const int hb = b * NHEADS + h;
    const int s0 = (qt - 8) * 2;
    const unsigned short* A  = Opart + ((size_t)(s0)*64 + hb) * 128 * 64;
    const unsigned short* Bp = Opart + ((size_t)(s0 + 1) * 64 + hb) * 128 * 64;
    const float* LA = Lpart + ((size_t)(s0)*64 + hb) * 128;
    const float* LB = Lpart + ((size_t)(s0 + 1) * 64 + hb) * 128;
    // 128*64 elems = 2048 ushort4; 256 threads x 8 iters
    for (int e4 = threadIdx.x; e4 < 2048; e4 += 256) {
        const int qr = e4 >> 4, d4 = (e4 & 15) * 4;
        const float inv = 1.f / (LA[qr] + LB[qr]);
        ushort4 a = *(const ushort4*)&A[(size_t)qr * 64 + d4];
        ushort4 p = *(const ushort4*)&Bp[(size_t)qr * 64 + d4];
        ushort4 o;
        o.x = f2bf((bf2f(a.x) + bf2f(p.x)) * inv);
        o.y = f2bf((bf2f(a.y) + bf2f(p.y)) * inv);
        o.z = f2bf((bf2f(a.z) + bf2f(p.z)) * inv);
        o.w = f2bf((bf2f(a.w) + bf2f(p.w)) * inv);
        *(ushort4*)&O[(size_t)(b * SEQ + qt * 128 + qr) * D_MODEL + h * DK + d4] = o;
    }
}

// ---------------- launch ----------------

extern "C" void kernel_launch(void* const* d_in, const int* in_sizes, int n_in,
                              void* d_out, int out_size, void* d_ws, size_t ws_size,
                              hipStream_t stream) {
    const float* x  = (const float*)d_in[0];
    const float* wq = (const float*)d_in[1];
    const float* bq = (const float*)d_in[2];
    const float* wk = (const float*)d_in[3];
    const float* bk = (const float*)d_in[4];
    const float* wv = (const float*)d_in[5];
    const float* bv = (const float*)d_in[6];
    const float* wo = (const float*)d_in[7];
    const float* bo = (const float*)d_in[8];
    float* out = (float*)d_out;

    char* ws = (char*)d_ws;
    const size_t MB = 1u << 20;
    unsigned short* xb    = (unsigned short*)(ws);            // 16 MB  x bf16
    unsigned short* wqkvt = (unsigned short*)(ws + 16 * MB);  //  6 MB  [Wq;Wk;Wv]^T
    unsigned short* wot   = (unsigned short*)(ws + 22 * MB);  //  2 MB (live thru out-proj)
    unsigned short* qb    = (unsigned short*)(ws + 24 * MB);  // 16 MB each
    unsigned short* kb    = (unsigned short*)(ws + 40 * MB);
    unsigned short* vtb   = (unsigned short*)(ws + 56 * MB);  // V^T (B,H,Dk,S)
    unsigned short* ab    = (unsigned short*)(ws + 72 * MB);  // attn out, ends 88 MB
    float* cbias = (float*)(ws + 72 * MB);  // 12 KB, consumed by QKV GEMM
    // split-K partials overlay xb/wqkvt (dead after the QKV GEMM):
    unsigned short* Opart = (unsigned short*)(ws);  // 16 MB [16][64][128][64] bf16
    float* Lpart = (float*)(ws + 16 * MB);          // 512 KB [16][64][128] fp32

    f32_to_bf16_k<<<(MROWS * D_MODEL / 4 + 255) / 256, 256, 0, stream>>>(
        x, xb, MROWS * D_MODEL / 4);
    transpose_all_k<<<dim3(32, 32, 4), 256, 0, stream>>>(wq, wk, wv, wo, wqkvt, wot);
    build_cbias_k<<<12, 256, 0, stream>>>(bq, bk, bv, cbias);

    // Q pre-scale folds softmax's 1/sqrt(Dk) AND log2(e) for exp2-domain softmax
    const float QSCALE = 0.125f * 1.44269504088896340736f;

    // fused QKV projection: N = 3072
    gemm_glds<<<dim3(3072 / 128, MROWS / 128), 256, 0, stream>>>(
        xb, wqkvt, cbias, qb, kb, vtb, nullptr, QSCALE, 0);

    attn_mfmaA<<<dim3(24, NHEADS, BATCH), 256, 0, stream>>>(
        qb, kb, vtb, ab, Opart, Lpart);
    attn_combine_k<<<dim3(8, NHEADS, BATCH), 256, 0, stream>>>(Opart, Lpart, ab);

    // out projection: fp32 output + bias
    gemm_glds<<<dim3(D_MODEL / 128, MROWS / 128), 256, 0, stream>>>(
        ab, wot, bo, nullptr, nullptr, nullptr, out, 1.0f, 1);
}